// Round 4
// baseline (305.839 us; speedup 1.0000x reference)
//
#include <hip/hip_runtime.h>
#include <stdint.h>

// Forbid FMA contraction so float32 results mirror XLA-CPU's non-contracted
// elementwise arithmetic (iou>=0.5 and round(0.5) boundaries).
#pragma clang fp contract(off)

#define NB 16
#define NPROP 2000
#define MAXGT 100
#define NUMPOS 66
#define NUMNEG 134
#define NROIS 200
#define IMH 160
#define IMW 160
#define MHH 28
#define MWW 28
#define SBLK 512

#define ROIS_OFF 0
#define CLS_OFF (NB * NROIS * 4)               /* 12800 */
#define DELTA_OFF (CLS_OFF + NB * NROIS)       /* 16000 */
#define MASK_OFF (DELTA_OFF + NB * NROIS * 4)  /* 28800 */

__device__ __forceinline__ unsigned rotl32(unsigned v, int d) {
  return (v << d) | (v >> (32 - d));
}

// JAX threefry2x32 (jax/_src/prng.py), 20 rounds, key schedule +1..+5.
__device__ void threefry2x32(unsigned k0, unsigned k1, unsigned c0, unsigned c1,
                             unsigned &o0, unsigned &o1) {
  const unsigned ks2 = k0 ^ k1 ^ 0x1BD11BDAu;
  unsigned x0 = c0 + k0;
  unsigned x1 = c1 + k1;
  const int rA[4] = {13, 15, 26, 6};
  const int rB[4] = {17, 29, 16, 24};
#pragma unroll
  for (int i = 0; i < 4; i++) { x0 += x1; x1 = rotl32(x1, rA[i]); x1 ^= x0; }
  x0 += k1;  x1 += ks2 + 1u;
#pragma unroll
  for (int i = 0; i < 4; i++) { x0 += x1; x1 = rotl32(x1, rB[i]); x1 ^= x0; }
  x0 += ks2; x1 += k0 + 2u;
#pragma unroll
  for (int i = 0; i < 4; i++) { x0 += x1; x1 = rotl32(x1, rA[i]); x1 ^= x0; }
  x0 += k0;  x1 += k1 + 3u;
#pragma unroll
  for (int i = 0; i < 4; i++) { x0 += x1; x1 = rotl32(x1, rB[i]); x1 ^= x0; }
  x0 += k1;  x1 += ks2 + 4u;
#pragma unroll
  for (int i = 0; i < 4; i++) { x0 += x1; x1 = rotl32(x1, rA[i]); x1 ^= x0; }
  x0 += ks2; x1 += k0 + 5u;
  o0 = x0; o1 = x1;
}

// Partitionable random_bits (32-bit): bits[i] = xor of the two output words of
// threefry(key, (0, i)); uniform = bitcast((bits>>9)|0x3f800000) - 1.
__device__ __forceinline__ float tf_uniform01(unsigned k0, unsigned k1,
                                              unsigned i) {
  unsigned a, b;
  threefry2x32(k0, k1, 0u, i, a, b);
  unsigned bits = a ^ b;
  return __uint_as_float((bits >> 9) | 0x3f800000u) - 1.0f;
}

// ---------------------------------------------------------------------------
// Fused select kernel: grid NB*2 x 512. Each (image, pos/neg) block:
//   scores all 2000 proposals (IoU argmax over 100 GT in LDS + threefry
//   uniform) entirely in LDS -> histogram -> single-wave shfl suffix scan ->
//   compact -> all-pairs stable rank (lax.top_k: score desc, index asc) ->
//   writes its half of rois/cls/deltas (+ ws_slots from the pos block).
// No global score round-trip, one launch instead of two.
// ---------------------------------------------------------------------------
__global__ __launch_bounds__(SBLK) void dtl_sel_kernel(
    const float* __restrict__ proposals,   // [NB,NPROP,4]
    const int* __restrict__ gt_class,      // [NB,MAXGT]
    const float* __restrict__ gt_boxes,    // [NB,MAXGT,4]
    const float* __restrict__ std_dev,     // [4]
    float* __restrict__ out,
    int* __restrict__ ws_slots) {          // [NB,NUMPOS,2]
#pragma clang fp contract(off)
  const int b = blockIdx.x >> 1;
  const bool is_pos = (blockIdx.x & 1) == 0;
  const int K = is_pos ? NUMPOS : NUMNEG;
  const int tid = threadIdx.x;

  __shared__ float s_gt[MAXGT][4];
  __shared__ float s_area[MAXGT];
  __shared__ int s_gtvalid[MAXGT];
  __shared__ int s_gtcls[MAXGT];
  __shared__ float s_sc[NPROP];
  __shared__ unsigned char s_arg[NPROP];
  __shared__ int s_hist[256];
  __shared__ int s_cand_i[NPROP];
  __shared__ float s_cand_s[NPROP];
  __shared__ int s_slot_i[NUMNEG];
  __shared__ float s_slot_s[NUMNEG];
  __shared__ int s_misc[4];  // 0: compact count, 1: T, 2: exact P count

  for (int g = tid; g < MAXGT; g += SBLK) {
    int cls = gt_class[b * MAXGT + g];
    s_gtcls[g] = cls;
    s_gtvalid[g] = (cls > 0) ? 1 : 0;
    float4 gb = ((const float4*)gt_boxes)[b * MAXGT + g];
    s_gt[g][0] = gb.x; s_gt[g][1] = gb.y; s_gt[g][2] = gb.z; s_gt[g][3] = gb.w;
    s_area[g] = (gb.z - gb.x) * (gb.w - gb.y);
  }
  if (tid < 256) s_hist[tid] = 0;
  if (tid < 4) s_misc[tid] = 0;
  __syncthreads();

  // key chain: root=(0,42); kb=tf(root,0,b); kp=tf(kb,0,0); kn=tf(kb,0,1)
  unsigned kb0, kb1, kp0, kp1, kn0, kn1;
  threefry2x32(0u, 42u, 0u, (unsigned)b, kb0, kb1);
  threefry2x32(kb0, kb1, 0u, 0u, kp0, kp1);
  threefry2x32(kb0, kb1, 0u, 1u, kn0, kn1);

  int pcnt = 0;  // (neg block) exact count of positives with u_pos > 0
  for (int i = tid; i < NPROP; i += SBLK) {
    float4 pb = ((const float4*)proposals)[b * NPROP + i];
    float p0 = pb.x, p1 = pb.y, p2 = pb.z, p3 = pb.w;
    bool vp = (p0 != 0.0f) || (p1 != 0.0f) || (p2 != 0.0f) || (p3 != 0.0f);
    float a1 = (p2 - p0) * (p3 - p1);
    float best = -2.0f;
    int arg = 0;
    for (int g = 0; g < MAXGT; ++g) {
      float yA = fmaxf(p0, s_gt[g][0]);
      float xA = fmaxf(p1, s_gt[g][1]);
      float yB = fminf(p2, s_gt[g][2]);
      float xB = fminf(p3, s_gt[g][3]);
      float inter = fmaxf(yB - yA, 0.0f) * fmaxf(xB - xA, 0.0f);
      float uni = (a1 + s_area[g]) - inter;
      float iou = inter / fmaxf(uni, 1e-10f);
      float v = s_gtvalid[g] ? iou : -1.0f;
      if (v > best) { best = v; arg = g; }  // strict >: first-occurrence argmax
    }
    bool pos = (best >= 0.5f) && vp;
    bool neg = (best < 0.5f) && vp;
    float sc = -1.0f;
    if (is_pos) {
      if (pos) sc = tf_uniform01(kp0, kp1, (unsigned)i);
      s_arg[i] = (unsigned char)arg;
    } else {
      if (pos) pcnt += (tf_uniform01(kp0, kp1, (unsigned)i) > 0.0f) ? 1 : 0;
      if (neg) sc = tf_uniform01(kn0, kn1, (unsigned)i);
    }
    s_sc[i] = sc;
    if (sc >= 0.0f) {
      int bin = (int)(sc * 256.0f); if (bin > 255) bin = 255;
      atomicAdd(&s_hist[bin], 1);
    }
  }
  if (!is_pos && pcnt) atomicAdd(&s_misc[2], pcnt);
  __syncthreads();

  // Single-wave suffix scan: lane l owns bins 4l..4l+3. T = max bin v with
  // suffix[v] >= K (stays 0 if none).
  if (tid < 64) {
    int l = tid;
    int h0 = s_hist[4 * l + 0], h1 = s_hist[4 * l + 1];
    int h2 = s_hist[4 * l + 2], h3 = s_hist[4 * l + 3];
    int t = h0 + h1 + h2 + h3;
    int s = t;  // inclusive suffix over lane totals
#pragma unroll
    for (int d = 1; d < 64; d <<= 1) {
      int v = __shfl_down(s, d, 64);
      if (l + d < 64) s += v;
    }
    int S_excl = s - t;  // suffix at bin 4(l+1)
    int suf3 = h3 + S_excl;
    int suf2 = h2 + suf3;
    int suf1 = h1 + suf2;
    int suf0 = h0 + suf1;
    if (suf0 >= K && suf1 < K) s_misc[1] = 4 * l + 0;
    if (suf1 >= K && suf2 < K) s_misc[1] = 4 * l + 1;
    if (suf2 >= K && suf3 < K) s_misc[1] = 4 * l + 2;
    if (suf3 >= K && (l == 63 || S_excl < K)) s_misc[1] = 4 * l + 3;
  }
  for (int j = tid; j < K; j += SBLK) { s_slot_i[j] = -1; s_slot_s[j] = -1.0f; }
  __syncthreads();
  const int T = s_misc[1];

  // compact candidates in bins >= T
  for (int i = tid; i < NPROP; i += SBLK) {
    float s = s_sc[i];
    if (s >= 0.0f) {
      int bin = (int)(s * 256.0f); if (bin > 255) bin = 255;
      if (bin >= T) {
        int t = atomicAdd(&s_misc[0], 1);
        s_cand_i[t] = i; s_cand_s[t] = s;
      }
    }
  }
  __syncthreads();

  // all-pairs stable rank (C ~ K + O(NPROP/256), small)
  const int C = s_misc[0];
  for (int t = tid; t < C; t += SBLK) {
    float st = s_cand_s[t]; int it = s_cand_i[t];
    int r = 0;
    for (int u = 0; u < C; ++u) {
      float su = s_cand_s[u];
      r += (su > st) || (su == st && s_cand_i[u] < it);
    }
    if (r < K) { s_slot_i[r] = it; s_slot_s[r] = st; }
  }
  __syncthreads();

  if (is_pos) {
    const float sd0 = std_dev[0], sd1 = std_dev[1], sd2 = std_dev[2],
                sd3 = std_dev[3];
    for (int j = tid; j < NUMPOS; j += SBLK) {
      float r0 = 0, r1 = 0, r2 = 0, r3 = 0;
      float d0 = 0, d1 = 0, d2 = 0, d3 = 0;
      float cls = 0;
      int idx = s_slot_i[j];
      bool valid = (idx >= 0) && (s_slot_s[j] > 0.0f);
      int g = 0;
      if (valid) {
        float4 pb = ((const float4*)proposals)[b * NPROP + idx];
        r0 = pb.x; r1 = pb.y; r2 = pb.z; r3 = pb.w;
        g = (int)s_arg[idx];
        float g0 = s_gt[g][0], g1 = s_gt[g][1], g2 = s_gt[g][2],
              g3 = s_gt[g][3];
        float h = r2 - r0, w = r3 - r1;
        float cy = r0 + 0.5f * h, cx = r1 + 0.5f * w;
        float gh = g2 - g0, gw = g3 - g1;
        float gcy = g0 + 0.5f * gh, gcx = g1 + 0.5f * gw;
        d0 = ((gcy - cy) / h) / sd0;
        d1 = ((gcx - cx) / w) / sd1;
        d2 = logf(gh / h) / sd2;
        d3 = logf(gw / w) / sd3;
        cls = (float)s_gtcls[g];
      }
      ws_slots[(b * NUMPOS + j) * 2 + 0] = valid ? idx : -1;
      ws_slots[(b * NUMPOS + j) * 2 + 1] = g;
      out[ROIS_OFF + (b * NROIS + j) * 4 + 0] = r0;
      out[ROIS_OFF + (b * NROIS + j) * 4 + 1] = r1;
      out[ROIS_OFF + (b * NROIS + j) * 4 + 2] = r2;
      out[ROIS_OFF + (b * NROIS + j) * 4 + 3] = r3;
      out[CLS_OFF + b * NROIS + j] = cls;
      out[DELTA_OFF + (b * NROIS + j) * 4 + 0] = d0;
      out[DELTA_OFF + (b * NROIS + j) * 4 + 1] = d1;
      out[DELTA_OFF + (b * NROIS + j) * 4 + 2] = d2;
      out[DELTA_OFF + (b * NROIS + j) * 4 + 3] = d3;
    }
  } else {
    // P = min(exact positive count, NUMPOS);
    // neg_needed = trunc((float)P/0.33f) - P, clipped to [0, NUMNEG]
    int P = s_misc[2]; P = P > NUMPOS ? NUMPOS : P;
    int t = (int)((float)P / 0.33f);  // float32 div + trunc, as in reference
    int neg_needed = t - P;
    neg_needed = neg_needed < 0 ? 0 : neg_needed;
    neg_needed = neg_needed > NUMNEG ? NUMNEG : neg_needed;

    for (int jn = tid; jn < NUMNEG; jn += SBLK) {
      int j = NUMPOS + jn;
      float r0 = 0, r1 = 0, r2 = 0, r3 = 0;
      int idx = s_slot_i[jn];
      bool valid = (idx >= 0) && (s_slot_s[jn] > 0.0f) && (jn < neg_needed);
      if (valid) {
        float4 pb = ((const float4*)proposals)[b * NPROP + idx];
        r0 = pb.x; r1 = pb.y; r2 = pb.z; r3 = pb.w;
      }
      out[ROIS_OFF + (b * NROIS + j) * 4 + 0] = r0;
      out[ROIS_OFF + (b * NROIS + j) * 4 + 1] = r1;
      out[ROIS_OFF + (b * NROIS + j) * 4 + 2] = r2;
      out[ROIS_OFF + (b * NROIS + j) * 4 + 3] = r3;
      out[CLS_OFF + b * NROIS + j] = 0.0f;
      out[DELTA_OFF + (b * NROIS + j) * 4 + 0] = 0.0f;
      out[DELTA_OFF + (b * NROIS + j) * 4 + 1] = 0.0f;
      out[DELTA_OFF + (b * NROIS + j) * 4 + 2] = 0.0f;
      out[DELTA_OFF + (b * NROIS + j) * 4 + 3] = 0.0f;
    }
  }
}

// ---------------------------------------------------------------------------
// Mask crop_and_resize (unchanged from passing rounds).
// ---------------------------------------------------------------------------
__global__ __launch_bounds__(256) void dtl_mask_kernel(
    const float* __restrict__ proposals,  // [NB,NPROP,4]
    const float* __restrict__ gmasks,     // [NB,IMH,IMW,MAXGT]
    const int* __restrict__ ws_slots,     // [NB,NUMPOS,2]
    float* __restrict__ out) {
#pragma clang fp contract(off)
  const int bs = blockIdx.x;
  const int b = bs / NROIS;
  const int slot = bs % NROIS;
  float* mo = out + MASK_OFF + (size_t)(b * NROIS + slot) * (MHH * MWW);
  int pidx = -1, g = 0;
  if (slot < NUMPOS) {
    pidx = ws_slots[(b * NUMPOS + slot) * 2 + 0];
    g = ws_slots[(b * NUMPOS + slot) * 2 + 1];
  }
  if (pidx < 0) {
    for (int p = threadIdx.x; p < MHH * MWW; p += 256) mo[p] = 0.0f;
    return;
  }
  float4 bx = ((const float4*)proposals)[b * NPROP + pidx];
  const float y1 = bx.x, x1 = bx.y, y2 = bx.z, x2 = bx.w;
  const float* img = gmasks + (size_t)b * IMH * IMW * MAXGT + g;
  for (int p = threadIdx.x; p < MHH * MWW; p += 256) {
    int m = p / MWW, n = p % MWW;
    float ty = (float)m / (float)(MHH - 1);
    float tx = (float)n / (float)(MWW - 1);
    float ys = (y1 + ty * (y2 - y1)) * (float)(IMH - 1);
    float xs = (x1 + tx * (x2 - x1)) * (float)(IMW - 1);
    float y0f = floorf(ys), x0f = floorf(xs);
    float fy = ys - y0f, fx = xs - x0f;
    int y0 = (int)y0f; y0 = y0 < 0 ? 0 : (y0 > IMH - 1 ? IMH - 1 : y0);
    int y1i = y0 + 1;  y1i = y1i > IMH - 1 ? IMH - 1 : y1i;
    int x0 = (int)x0f; x0 = x0 < 0 ? 0 : (x0 > IMW - 1 ? IMW - 1 : x0);
    int x1i = x0 + 1;  x1i = x1i > IMW - 1 ? IMW - 1 : x1i;
    float m00 = img[((size_t)y0 * IMW + x0) * MAXGT];
    float m01 = img[((size_t)y0 * IMW + x1i) * MAXGT];
    float m10 = img[((size_t)y1i * IMW + x0) * MAXGT];
    float m11 = img[((size_t)y1i * IMW + x1i) * MAXGT];
    float v = m00 * (1.0f - fy) * (1.0f - fx)
            + m01 * (1.0f - fy) * fx
            + m10 * fy * (1.0f - fx)
            + m11 * fy * fx;
    mo[p] = rintf(v);  // jnp.round: half-to-even; * pos_valid(==1) implicit
  }
}

extern "C" void kernel_launch(void* const* d_in, const int* in_sizes, int n_in,
                              void* d_out, int out_size, void* d_ws,
                              size_t ws_size, hipStream_t stream) {
  const float* proposals = (const float*)d_in[0];
  const int* gt_class = (const int*)d_in[1];
  const float* gt_boxes = (const float*)d_in[2];
  const float* gmasks = (const float*)d_in[3];
  const float* std_dev = (const float*)d_in[4];
  float* out = (float*)d_out;
  int* ws_slots = (int*)d_ws;  // NB*NUMPOS*2 ints = 8448 B

  dtl_sel_kernel<<<NB * 2, SBLK, 0, stream>>>(proposals, gt_class, gt_boxes,
                                              std_dev, out, ws_slots);
  dtl_mask_kernel<<<NB * NROIS, 256, 0, stream>>>(proposals, gmasks, ws_slots,
                                                  out);
}

// Round 5
// 271.541 us; speedup vs baseline: 1.1263x; 1.1263x over previous
//
#include <hip/hip_runtime.h>
#include <stdint.h>

// Forbid FMA contraction so float32 results mirror XLA-CPU's non-contracted
// elementwise arithmetic (iou>=0.5 and round(0.5) boundaries).
#pragma clang fp contract(off)

#define NB 16
#define NPROP 2000
#define MAXGT 100
#define NUMPOS 66
#define NUMNEG 134
#define NROIS 200
#define IMH 160
#define IMW 160
#define MHH 28
#define MWW 28
#define BLK 256

#define ROIS_OFF 0
#define CLS_OFF (NB * NROIS * 4)               /* 12800 */
#define DELTA_OFF (CLS_OFF + NB * NROIS)       /* 16000 */
#define MASK_OFF (DELTA_OFF + NB * NROIS * 4)  /* 28800 */

__device__ __forceinline__ unsigned rotl32(unsigned v, int d) {
  return (v << d) | (v >> (32 - d));
}

// JAX threefry2x32 (jax/_src/prng.py), 20 rounds, key schedule +1..+5.
__device__ void threefry2x32(unsigned k0, unsigned k1, unsigned c0, unsigned c1,
                             unsigned &o0, unsigned &o1) {
  const unsigned ks2 = k0 ^ k1 ^ 0x1BD11BDAu;
  unsigned x0 = c0 + k0;
  unsigned x1 = c1 + k1;
  const int rA[4] = {13, 15, 26, 6};
  const int rB[4] = {17, 29, 16, 24};
#pragma unroll
  for (int i = 0; i < 4; i++) { x0 += x1; x1 = rotl32(x1, rA[i]); x1 ^= x0; }
  x0 += k1;  x1 += ks2 + 1u;
#pragma unroll
  for (int i = 0; i < 4; i++) { x0 += x1; x1 = rotl32(x1, rB[i]); x1 ^= x0; }
  x0 += ks2; x1 += k0 + 2u;
#pragma unroll
  for (int i = 0; i < 4; i++) { x0 += x1; x1 = rotl32(x1, rA[i]); x1 ^= x0; }
  x0 += k0;  x1 += k1 + 3u;
#pragma unroll
  for (int i = 0; i < 4; i++) { x0 += x1; x1 = rotl32(x1, rB[i]); x1 ^= x0; }
  x0 += k1;  x1 += ks2 + 4u;
#pragma unroll
  for (int i = 0; i < 4; i++) { x0 += x1; x1 = rotl32(x1, rA[i]); x1 ^= x0; }
  x0 += ks2; x1 += k0 + 5u;
  o0 = x0; o1 = x1;
}

// Partitionable random_bits (32-bit): bits[i] = xor of the two output words of
// threefry(key, (0, i)); uniform = bitcast((bits>>9)|0x3f800000) - 1.
__device__ __forceinline__ float tf_uniform01(unsigned k0, unsigned k1,
                                              unsigned i) {
  unsigned a, b;
  threefry2x32(k0, k1, 0u, i, a, b);
  unsigned bits = a ^ b;
  return __uint_as_float((bits >> 9) | 0x3f800000u) - 1.0f;
}

// ---------------------------------------------------------------------------
// Kernel 1: per-proposal scoring. grid (8, NB) x 256 threads, one thread per
// proposal: IoU argmax over 100 GT (LDS), threefry uniform for the branch the
// proposal falls in. Per-block keys hoisted to LDS (thread 0) -- only the
// per-proposal uniform varies per thread.
// ---------------------------------------------------------------------------
__global__ __launch_bounds__(BLK) void dtl_score_kernel(
    const float* __restrict__ proposals,   // [NB,NPROP,4]
    const int* __restrict__ gt_class,      // [NB,MAXGT]
    const float* __restrict__ gt_boxes,    // [NB,MAXGT,4]
    float* __restrict__ ws_pos_s,          // [NB,NPROP]
    float* __restrict__ ws_neg_s,          // [NB,NPROP]
    unsigned char* __restrict__ ws_arg) {  // [NB,NPROP]
#pragma clang fp contract(off)
  const int b = blockIdx.y;
  const int i = blockIdx.x * BLK + threadIdx.x;

  __shared__ float s_gt[MAXGT][4];
  __shared__ float s_area[MAXGT];
  __shared__ int s_gtvalid[MAXGT];
  __shared__ unsigned s_keys[4];  // kp0,kp1,kn0,kn1
  for (int g = threadIdx.x; g < MAXGT; g += BLK) {
    s_gtvalid[g] = (gt_class[b * MAXGT + g] > 0) ? 1 : 0;
    float4 gb = ((const float4*)gt_boxes)[b * MAXGT + g];
    s_gt[g][0] = gb.x; s_gt[g][1] = gb.y; s_gt[g][2] = gb.z; s_gt[g][3] = gb.w;
    s_area[g] = (gb.z - gb.x) * (gb.w - gb.y);
  }
  if (threadIdx.x == 0) {
    // key chain: root=(0,42); kb=tf(root,0,b); kp=tf(kb,0,0); kn=tf(kb,0,1)
    unsigned kb0, kb1, k0, k1;
    threefry2x32(0u, 42u, 0u, (unsigned)b, kb0, kb1);
    threefry2x32(kb0, kb1, 0u, 0u, k0, k1);
    s_keys[0] = k0; s_keys[1] = k1;
    threefry2x32(kb0, kb1, 0u, 1u, k0, k1);
    s_keys[2] = k0; s_keys[3] = k1;
  }
  __syncthreads();
  if (i >= NPROP) return;

  float4 pb = ((const float4*)proposals)[b * NPROP + i];
  float p0 = pb.x, p1 = pb.y, p2 = pb.z, p3 = pb.w;
  bool vp = (p0 != 0.0f) || (p1 != 0.0f) || (p2 != 0.0f) || (p3 != 0.0f);
  float a1 = (p2 - p0) * (p3 - p1);
  float best = -2.0f;
  int arg = 0;
  for (int g = 0; g < MAXGT; ++g) {
    float yA = fmaxf(p0, s_gt[g][0]);
    float xA = fmaxf(p1, s_gt[g][1]);
    float yB = fminf(p2, s_gt[g][2]);
    float xB = fminf(p3, s_gt[g][3]);
    float inter = fmaxf(yB - yA, 0.0f) * fmaxf(xB - xA, 0.0f);
    float uni = (a1 + s_area[g]) - inter;
    float iou = inter / fmaxf(uni, 1e-10f);
    float v = s_gtvalid[g] ? iou : -1.0f;
    if (v > best) { best = v; arg = g; }  // strict > : first-occurrence argmax
  }

  float pos_s = -1.0f, neg_s = -1.0f;
  if (vp) {
    bool pos = (best >= 0.5f);
    unsigned k0 = pos ? s_keys[0] : s_keys[2];
    unsigned k1 = pos ? s_keys[1] : s_keys[3];
    float u = tf_uniform01(k0, k1, (unsigned)i);
    if (pos) pos_s = u; else neg_s = u;
  }
  ws_pos_s[b * NPROP + i] = pos_s;
  ws_neg_s[b * NPROP + i] = neg_s;
  ws_arg[b * NPROP + i] = (unsigned char)arg;
}

// ---------------------------------------------------------------------------
// Kernel 2: per-(image, pos/neg) stable top-K + output writing.
// grid NB*2 x 256. Histogram (global reads, L2-hot) -> single-wave shfl
// suffix-scan over 256 bins (0 barriers) -> threshold bin -> compact ->
// all-pairs stable rank (lax.top_k: score desc, index asc).
// ---------------------------------------------------------------------------
__global__ __launch_bounds__(BLK) void dtl_topk_kernel(
    const float* __restrict__ proposals,
    const int* __restrict__ gt_class,
    const float* __restrict__ gt_boxes,
    const float* __restrict__ std_dev,
    const float* __restrict__ ws_pos_s,
    const float* __restrict__ ws_neg_s,
    const unsigned char* __restrict__ ws_arg,
    float* __restrict__ out,
    int* __restrict__ ws_slots) {
#pragma clang fp contract(off)
  const int b = blockIdx.x >> 1;
  const bool is_pos = (blockIdx.x & 1) == 0;
  const int K = is_pos ? NUMPOS : NUMNEG;
  const int tid = threadIdx.x;

  __shared__ int s_hist[256];
  __shared__ int s_cand_i[NPROP];
  __shared__ float s_cand_s[NPROP];
  __shared__ int s_slot_i[NUMNEG];
  __shared__ float s_slot_s[NUMNEG];
  __shared__ float s_gt[MAXGT][4];
  __shared__ int s_gtcls[MAXGT];
  __shared__ int s_misc[4];  // 0: compact count, 1: T, 2: pos count

  const float* sc_g = (is_pos ? ws_pos_s : ws_neg_s) + (size_t)b * NPROP;
  if (is_pos) {
    for (int g = tid; g < MAXGT; g += BLK) {
      s_gtcls[g] = gt_class[b * MAXGT + g];
      float4 gb = ((const float4*)gt_boxes)[b * MAXGT + g];
      s_gt[g][0] = gb.x; s_gt[g][1] = gb.y; s_gt[g][2] = gb.z; s_gt[g][3] = gb.w;
    }
  }
  s_hist[tid] = 0;
  if (tid < 4) s_misc[tid] = 0;
  __syncthreads();

  // histogram (256 bins over [0,1)), straight from global (L2-hot, coalesced)
  for (int i = tid; i < NPROP; i += BLK) {
    float s = sc_g[i];
    if (s >= 0.0f) {
      int bin = (int)(s * 256.0f); if (bin > 255) bin = 255;
      atomicAdd(&s_hist[bin], 1);
    }
  }
  __syncthreads();

  // Single-wave suffix scan: lane l owns bins 4l..4l+3. T = max bin v with
  // suffix[v] >= K (0 if none).
  if (tid < 64) {
    int l = tid;
    int h0 = s_hist[4 * l + 0], h1 = s_hist[4 * l + 1];
    int h2 = s_hist[4 * l + 2], h3 = s_hist[4 * l + 3];
    int t = h0 + h1 + h2 + h3;
    int s = t;  // inclusive suffix over lane totals (shfl_down)
#pragma unroll
    for (int d = 1; d < 64; d <<= 1) {
      int v = __shfl_down(s, d, 64);
      if (l + d < 64) s += v;
    }
    int S_excl = s - t;            // = suffix at bin 4(l+1)
    int suf3 = h3 + S_excl;
    int suf2 = h2 + suf3;
    int suf1 = h1 + suf2;
    int suf0 = h0 + suf1;
    if (suf0 >= K && suf1 < K) s_misc[1] = 4 * l + 0;
    if (suf1 >= K && suf2 < K) s_misc[1] = 4 * l + 1;
    if (suf2 >= K && suf3 < K) s_misc[1] = 4 * l + 2;
    if (suf3 >= K && (l == 63 || S_excl < K)) s_misc[1] = 4 * l + 3;
  }
  for (int j = tid; j < K; j += BLK) { s_slot_i[j] = -1; s_slot_s[j] = -1.0f; }
  __syncthreads();
  const int T = s_misc[1];

  // compact candidates in bins >= T
  for (int i = tid; i < NPROP; i += BLK) {
    float s = sc_g[i];
    if (s >= 0.0f) {
      int bin = (int)(s * 256.0f); if (bin > 255) bin = 255;
      if (bin >= T) {
        int t = atomicAdd(&s_misc[0], 1);
        s_cand_i[t] = i; s_cand_s[t] = s;
      }
    }
  }
  __syncthreads();

  // all-pairs stable rank (C ~ K + NPROP/256, small)
  const int C = s_misc[0];
  for (int t = tid; t < C; t += BLK) {
    float st = s_cand_s[t]; int it = s_cand_i[t];
    int r = 0;
    for (int u = 0; u < C; ++u) {
      float su = s_cand_s[u];
      r += (su > st) || (su == st && s_cand_i[u] < it);
    }
    if (r < K) { s_slot_i[r] = it; s_slot_s[r] = st; }
  }
  __syncthreads();

  if (is_pos) {
    const float sd0 = std_dev[0], sd1 = std_dev[1], sd2 = std_dev[2],
                sd3 = std_dev[3];
    for (int j = tid; j < NUMPOS; j += BLK) {
      float r0 = 0, r1 = 0, r2 = 0, r3 = 0;
      float d0 = 0, d1 = 0, d2 = 0, d3 = 0;
      float cls = 0;
      int idx = s_slot_i[j];
      bool valid = (idx >= 0) && (s_slot_s[j] > 0.0f);
      int g = 0;
      if (valid) {
        float4 pb = ((const float4*)proposals)[b * NPROP + idx];
        r0 = pb.x; r1 = pb.y; r2 = pb.z; r3 = pb.w;
        g = (int)ws_arg[(size_t)b * NPROP + idx];
        float g0 = s_gt[g][0], g1 = s_gt[g][1], g2 = s_gt[g][2],
              g3 = s_gt[g][3];
        float h = r2 - r0, w = r3 - r1;
        float cy = r0 + 0.5f * h, cx = r1 + 0.5f * w;
        float gh = g2 - g0, gw = g3 - g1;
        float gcy = g0 + 0.5f * gh, gcx = g1 + 0.5f * gw;
        d0 = ((gcy - cy) / h) / sd0;
        d1 = ((gcx - cx) / w) / sd1;
        d2 = logf(gh / h) / sd2;
        d3 = logf(gw / w) / sd3;
        cls = (float)s_gtcls[g];
      }
      ws_slots[(b * NUMPOS + j) * 2 + 0] = valid ? idx : -1;
      ws_slots[(b * NUMPOS + j) * 2 + 1] = g;
      out[ROIS_OFF + (b * NROIS + j) * 4 + 0] = r0;
      out[ROIS_OFF + (b * NROIS + j) * 4 + 1] = r1;
      out[ROIS_OFF + (b * NROIS + j) * 4 + 2] = r2;
      out[ROIS_OFF + (b * NROIS + j) * 4 + 3] = r3;
      out[CLS_OFF + b * NROIS + j] = cls;
      out[DELTA_OFF + (b * NROIS + j) * 4 + 0] = d0;
      out[DELTA_OFF + (b * NROIS + j) * 4 + 1] = d1;
      out[DELTA_OFF + (b * NROIS + j) * 4 + 2] = d2;
      out[DELTA_OFF + (b * NROIS + j) * 4 + 3] = d3;
    }
  } else {
    // P = min(#{pos_s > 0}, NUMPOS); neg_needed = trunc(P/0.33f) - P, clipped
    {
      int cnt = 0;
      const float* ps = ws_pos_s + (size_t)b * NPROP;
      for (int i = tid; i < NPROP; i += BLK) cnt += (ps[i] > 0.0f) ? 1 : 0;
      atomicAdd(&s_misc[2], cnt);
    }
    __syncthreads();
    int P = s_misc[2]; P = P > NUMPOS ? NUMPOS : P;
    int t = (int)((float)P / 0.33f);  // float32 div + trunc, as in reference
    int neg_needed = t - P;
    neg_needed = neg_needed < 0 ? 0 : neg_needed;
    neg_needed = neg_needed > NUMNEG ? NUMNEG : neg_needed;

    for (int jn = tid; jn < NUMNEG; jn += BLK) {
      int j = NUMPOS + jn;
      float r0 = 0, r1 = 0, r2 = 0, r3 = 0;
      int idx = s_slot_i[jn];
      bool valid = (idx >= 0) && (s_slot_s[jn] > 0.0f) && (jn < neg_needed);
      if (valid) {
        float4 pb = ((const float4*)proposals)[b * NPROP + idx];
        r0 = pb.x; r1 = pb.y; r2 = pb.z; r3 = pb.w;
      }
      out[ROIS_OFF + (b * NROIS + j) * 4 + 0] = r0;
      out[ROIS_OFF + (b * NROIS + j) * 4 + 1] = r1;
      out[ROIS_OFF + (b * NROIS + j) * 4 + 2] = r2;
      out[ROIS_OFF + (b * NROIS + j) * 4 + 3] = r3;
      out[CLS_OFF + b * NROIS + j] = 0.0f;
      out[DELTA_OFF + (b * NROIS + j) * 4 + 0] = 0.0f;
      out[DELTA_OFF + (b * NROIS + j) * 4 + 1] = 0.0f;
      out[DELTA_OFF + (b * NROIS + j) * 4 + 2] = 0.0f;
      out[DELTA_OFF + (b * NROIS + j) * 4 + 3] = 0.0f;
    }
  }
}

// ---------------------------------------------------------------------------
// Kernel 3: mask crop_and_resize. The [H,W,G] layout makes the 4 bilinear
// taps structurally uncoalesced (stride 400 B); a transpose costs more
// traffic than it saves (328 MB vs ~100-200 MB of wasted line fetch).
// ---------------------------------------------------------------------------
__global__ __launch_bounds__(256) void dtl_mask_kernel(
    const float* __restrict__ proposals,  // [NB,NPROP,4]
    const float* __restrict__ gmasks,     // [NB,IMH,IMW,MAXGT]
    const int* __restrict__ ws_slots,     // [NB,NUMPOS,2]
    float* __restrict__ out) {
#pragma clang fp contract(off)
  const int bs = blockIdx.x;
  const int b = bs / NROIS;
  const int slot = bs % NROIS;
  float* mo = out + MASK_OFF + (size_t)(b * NROIS + slot) * (MHH * MWW);
  int pidx = -1, g = 0;
  if (slot < NUMPOS) {
    pidx = ws_slots[(b * NUMPOS + slot) * 2 + 0];
    g = ws_slots[(b * NUMPOS + slot) * 2 + 1];
  }
  if (pidx < 0) {
    for (int p = threadIdx.x; p < MHH * MWW; p += 256) mo[p] = 0.0f;
    return;
  }
  float4 bx = ((const float4*)proposals)[b * NPROP + pidx];
  const float y1 = bx.x, x1 = bx.y, y2 = bx.z, x2 = bx.w;
  const float* img = gmasks + (size_t)b * IMH * IMW * MAXGT + g;
  for (int p = threadIdx.x; p < MHH * MWW; p += 256) {
    int m = p / MWW, n = p % MWW;
    float ty = (float)m / (float)(MHH - 1);
    float tx = (float)n / (float)(MWW - 1);
    float ys = (y1 + ty * (y2 - y1)) * (float)(IMH - 1);
    float xs = (x1 + tx * (x2 - x1)) * (float)(IMW - 1);
    float y0f = floorf(ys), x0f = floorf(xs);
    float fy = ys - y0f, fx = xs - x0f;
    int y0 = (int)y0f; y0 = y0 < 0 ? 0 : (y0 > IMH - 1 ? IMH - 1 : y0);
    int y1i = y0 + 1;  y1i = y1i > IMH - 1 ? IMH - 1 : y1i;
    int x0 = (int)x0f; x0 = x0 < 0 ? 0 : (x0 > IMW - 1 ? IMW - 1 : x0);
    int x1i = x0 + 1;  x1i = x1i > IMW - 1 ? IMW - 1 : x1i;
    float m00 = img[((size_t)y0 * IMW + x0) * MAXGT];
    float m01 = img[((size_t)y0 * IMW + x1i) * MAXGT];
    float m10 = img[((size_t)y1i * IMW + x0) * MAXGT];
    float m11 = img[((size_t)y1i * IMW + x1i) * MAXGT];
    float v = m00 * (1.0f - fy) * (1.0f - fx)
            + m01 * (1.0f - fy) * fx
            + m10 * fy * (1.0f - fx)
            + m11 * fy * fx;
    mo[p] = rintf(v);  // jnp.round: half-to-even; * pos_valid(==1) implicit
  }
}

extern "C" void kernel_launch(void* const* d_in, const int* in_sizes, int n_in,
                              void* d_out, int out_size, void* d_ws,
                              size_t ws_size, hipStream_t stream) {
  const float* proposals = (const float*)d_in[0];
  const int* gt_class = (const int*)d_in[1];
  const float* gt_boxes = (const float*)d_in[2];
  const float* gmasks = (const float*)d_in[3];
  const float* std_dev = (const float*)d_in[4];
  float* out = (float*)d_out;

  // ws layout: pos_s [NB*NPROP f32] | neg_s [NB*NPROP f32] |
  //            slots [NB*NUMPOS*2 i32] | arg [NB*NPROP u8]   (~300 KB total)
  float* ws_pos_s = (float*)d_ws;
  float* ws_neg_s = ws_pos_s + NB * NPROP;
  int* ws_slots = (int*)(ws_neg_s + NB * NPROP);
  unsigned char* ws_arg = (unsigned char*)(ws_slots + NB * NUMPOS * 2);

  dim3 g1((NPROP + BLK - 1) / BLK, NB);
  dtl_score_kernel<<<g1, BLK, 0, stream>>>(proposals, gt_class, gt_boxes,
                                           ws_pos_s, ws_neg_s, ws_arg);
  dtl_topk_kernel<<<NB * 2, BLK, 0, stream>>>(proposals, gt_class, gt_boxes,
                                              std_dev, ws_pos_s, ws_neg_s,
                                              ws_arg, out, ws_slots);
  dtl_mask_kernel<<<NB * NROIS, 256, 0, stream>>>(proposals, gmasks, ws_slots,
                                                  out);
}